// Round 1
// baseline (609.693 us; speedup 1.0000x reference)
//
#include <hip/hip_runtime.h>

// ---------------------------------------------------------------------------
// 2-layer GCN on MI355X.
// Pipeline (all on `stream`, graph-capture safe):
//   1. zero deg/fill
//   2. deg[d] = #edges with dst==d          (int atomics)
//   3. dinv[n] = rsqrt(deg[n]+1)            (+1 = self loop)
//   4. row_ptr = exclusive_scan(deg)        (single-block scan)
//   5. CSR fill: ssrc sorted by dst         (int atomics for slots)
//   6. h1 = (x @ W1) * dinv[row]            (fp32 vector GEMM, K=128, NC=128)
//   7. out1 = relu(dinv[n]*(h1[n] + sum_{e->n} h1[src]) + b1)
//   8. h2 = (out1 @ W2) * dinv[row]         (K=128, NC=64)
//   9. d_out = dinv[n]*(h2[n] + sum h2[src]) + b2
// Normalization identity: sum_e h[src]*dinv[src]*dinv[dst]
//   = dinv[dst] * sum_e (h[src]*dinv[src])  -> fold dinv into GEMM epilogue.
// ---------------------------------------------------------------------------

__global__ void k_zero(int* __restrict__ p, int n) {
  int i = blockIdx.x * blockDim.x + threadIdx.x;
  int stride = gridDim.x * blockDim.x;
  for (; i < n; i += stride) p[i] = 0;
}

__global__ void k_deg(const int* __restrict__ dst, int E, int* __restrict__ deg) {
  int i = blockIdx.x * blockDim.x + threadIdx.x;
  int stride = gridDim.x * blockDim.x;
  for (; i < E; i += stride) atomicAdd(&deg[dst[i]], 1);
}

__global__ void k_dinv(const int* __restrict__ deg, float* __restrict__ dinv, int N) {
  int i = blockIdx.x * blockDim.x + threadIdx.x;
  if (i < N) dinv[i] = rsqrtf((float)(deg[i] + 1));
}

// Exclusive scan of deg[0..N) into row_ptr, single block of 1024 threads.
__global__ __launch_bounds__(1024) void k_scan(const int* __restrict__ deg,
                                               int* __restrict__ row_ptr, int N) {
  __shared__ int sums[1024];
  const int t = threadIdx.x;
  const int chunk = (N + 1023) >> 10;
  const int lo = t * chunk;
  const int hi = (lo + chunk < N) ? (lo + chunk) : N;
  int s = 0;
  for (int i = lo; i < hi; ++i) s += deg[i];
  sums[t] = s;
  __syncthreads();
  // Hillis-Steele inclusive scan over 1024 partials
  for (int off = 1; off < 1024; off <<= 1) {
    int add = (t >= off) ? sums[t - off] : 0;
    __syncthreads();
    sums[t] += add;
    __syncthreads();
  }
  int run = (t == 0) ? 0 : sums[t - 1];
  for (int i = lo; i < hi; ++i) { row_ptr[i] = run; run += deg[i]; }
}

__global__ void k_fill(const int* __restrict__ src, const int* __restrict__ dst, int E,
                       const int* __restrict__ row_ptr, int* __restrict__ fill,
                       int* __restrict__ ssrc) {
  int i = blockIdx.x * blockDim.x + threadIdx.x;
  int stride = gridDim.x * blockDim.x;
  for (; i < E; i += stride) {
    int d = dst[i];
    int pos = row_ptr[d] + atomicAdd(&fill[d], 1);
    ssrc[pos] = src[i];
  }
}

// H[row][c] = (sum_k X[row][k] * W[k][c]) * dinv[row].
// Block: 256 threads, 64 rows x NC cols. X staged transposed in LDS.
template <int NC>
__global__ __launch_bounds__(256) void k_gemm(const float* __restrict__ X,
                                              const float* __restrict__ W,
                                              const float* __restrict__ dinv,
                                              float* __restrict__ H, int N) {
  constexpr int K = 128;
  constexpr int BM = 64;
  constexpr int LDX = BM + 4;  // pad to break bank-conflict patterns on writes
  __shared__ float xs[K][LDX];
  const int t = threadIdx.x;
  const int r0 = blockIdx.x * BM;

  // Stage X^T: 64 rows x 128 cols, each thread 8 float4 loads.
  for (int idx = t; idx < BM * (K / 4); idx += 256) {
    int row = idx >> 5;   // /(K/4)
    int kg = idx & 31;    // %(K/4)
    float4 v = make_float4(0.f, 0.f, 0.f, 0.f);
    if (r0 + row < N)
      v = *reinterpret_cast<const float4*>(X + (size_t)(r0 + row) * K + 4 * kg);
    xs[4 * kg + 0][row] = v.x;
    xs[4 * kg + 1][row] = v.y;
    xs[4 * kg + 2][row] = v.z;
    xs[4 * kg + 3][row] = v.w;
  }
  __syncthreads();

  constexpr int CG = NC / 4;           // col-groups of 4
  constexpr int RPT = BM / (256 / CG); // rows per thread (8 for NC=128, 4 for NC=64)
  const int tx = t % CG;
  const int ty = t / CG;

  float acc[RPT][4];
#pragma unroll
  for (int r = 0; r < RPT; ++r) {
    acc[r][0] = 0.f; acc[r][1] = 0.f; acc[r][2] = 0.f; acc[r][3] = 0.f;
  }

#pragma unroll 4
  for (int k = 0; k < K; ++k) {
    const float4 w4 = *reinterpret_cast<const float4*>(W + (size_t)k * NC + 4 * tx);
    const float4* xr = reinterpret_cast<const float4*>(&xs[k][ty * RPT]);
#pragma unroll
    for (int rq = 0; rq < RPT / 4; ++rq) {
      float4 xv = xr[rq];
      float xe[4] = {xv.x, xv.y, xv.z, xv.w};
#pragma unroll
      for (int j = 0; j < 4; ++j) {
        int r = rq * 4 + j;
        acc[r][0] += xe[j] * w4.x;
        acc[r][1] += xe[j] * w4.y;
        acc[r][2] += xe[j] * w4.z;
        acc[r][3] += xe[j] * w4.w;
      }
    }
  }

#pragma unroll
  for (int r = 0; r < RPT; ++r) {
    int row = r0 + ty * RPT + r;
    if (row < N) {
      float dv = dinv[row];
      float4 o = make_float4(acc[r][0] * dv, acc[r][1] * dv, acc[r][2] * dv,
                             acc[r][3] * dv);
      *reinterpret_cast<float4*>(H + (size_t)row * NC + 4 * tx) = o;
    }
  }
}

// One wave per node: acc = H[n] + sum_{e: dst==n} H[ssrc[e]];
// out[n] = maybe_relu(acc * dinv[n] + bias).
template <int C, bool RELU>
__global__ __launch_bounds__(256) void k_agg(const float* __restrict__ H,
                                             const int* __restrict__ row_ptr,
                                             const int* __restrict__ deg,
                                             const int* __restrict__ ssrc,
                                             const float* __restrict__ dinv,
                                             const float* __restrict__ bias,
                                             float* __restrict__ out, int N) {
  const int wave = threadIdx.x >> 6;
  const int lane = threadIdx.x & 63;
  const int n = blockIdx.x * 4 + wave;
  if (n >= N) return;

  const int e0 = row_ptr[n];
  const int e1 = e0 + deg[n];
  const float dv = dinv[n];

  if constexpr (C == 128) {
    float2 acc = *reinterpret_cast<const float2*>(H + (size_t)n * C + 2 * lane);
    int e = e0;
    for (; e + 4 <= e1; e += 4) {
      int s0 = ssrc[e], s1 = ssrc[e + 1], s2 = ssrc[e + 2], s3 = ssrc[e + 3];
      float2 v0 = *reinterpret_cast<const float2*>(H + (size_t)s0 * C + 2 * lane);
      float2 v1 = *reinterpret_cast<const float2*>(H + (size_t)s1 * C + 2 * lane);
      float2 v2 = *reinterpret_cast<const float2*>(H + (size_t)s2 * C + 2 * lane);
      float2 v3 = *reinterpret_cast<const float2*>(H + (size_t)s3 * C + 2 * lane);
      acc.x += (v0.x + v1.x) + (v2.x + v3.x);
      acc.y += (v0.y + v1.y) + (v2.y + v3.y);
    }
    for (; e < e1; ++e) {
      int s = ssrc[e];
      float2 v = *reinterpret_cast<const float2*>(H + (size_t)s * C + 2 * lane);
      acc.x += v.x;
      acc.y += v.y;
    }
    float2 b = *reinterpret_cast<const float2*>(bias + 2 * lane);
    float ox = acc.x * dv + b.x;
    float oy = acc.y * dv + b.y;
    if (RELU) { ox = fmaxf(ox, 0.f); oy = fmaxf(oy, 0.f); }
    *reinterpret_cast<float2*>(out + (size_t)n * C + 2 * lane) = make_float2(ox, oy);
  } else {  // C == 64
    float acc = H[(size_t)n * C + lane];
    int e = e0;
    for (; e + 4 <= e1; e += 4) {
      int s0 = ssrc[e], s1 = ssrc[e + 1], s2 = ssrc[e + 2], s3 = ssrc[e + 3];
      float v0 = H[(size_t)s0 * C + lane];
      float v1 = H[(size_t)s1 * C + lane];
      float v2 = H[(size_t)s2 * C + lane];
      float v3 = H[(size_t)s3 * C + lane];
      acc += (v0 + v1) + (v2 + v3);
    }
    for (; e < e1; ++e) {
      int s = ssrc[e];
      acc += H[(size_t)s * C + lane];
    }
    float o = acc * dv + bias[lane];
    if (RELU) o = fmaxf(o, 0.f);
    out[(size_t)n * C + lane] = o;
  }
}

extern "C" void kernel_launch(void* const* d_in, const int* in_sizes, int n_in,
                              void* d_out, int out_size, void* d_ws, size_t ws_size,
                              hipStream_t stream) {
  const float* x = (const float*)d_in[0];
  const int* ei = (const int*)d_in[1];
  const float* W1 = (const float*)d_in[2];
  const float* b1 = (const float*)d_in[3];
  const float* W2 = (const float*)d_in[4];
  const float* b2 = (const float*)d_in[5];

  const int K = 128;                 // d_in == d_hid == 128
  const int N = in_sizes[0] / K;     // 100000
  const int E = in_sizes[1] / 2;     // 1600000
  const int NC2 = in_sizes[5];       // 64

  const int* src = ei;
  const int* dst = ei + E;

  // Workspace carve-up (256B aligned).
  size_t off = 0;
  auto carve = [&](size_t bytes) {
    size_t o = off;
    off += (bytes + 255) & ~(size_t)255;
    return o;
  };
  char* ws = (char*)d_ws;
  int*   deg     = (int*)(ws + carve((size_t)N * 4));
  int*   row_ptr = (int*)(ws + carve((size_t)N * 4));
  int*   fill    = (int*)(ws + carve((size_t)N * 4));
  float* dinv    = (float*)(ws + carve((size_t)N * 4));
  int*   ssrc    = (int*)(ws + carve((size_t)E * 4));
  float* h1      = (float*)(ws + carve((size_t)N * K * 4));   // reused as h2
  float* out1    = (float*)(ws + carve((size_t)N * K * 4));
  if (off > ws_size) return;  // workspace too small — nothing sane to do

  float* h2 = h1;  // h1 dead after agg1
  float* out2 = (float*)d_out;

  // 1. zero deg + fill
  k_zero<<<(N + 255) / 256, 256, 0, stream>>>(deg, N);
  k_zero<<<(N + 255) / 256, 256, 0, stream>>>(fill, N);
  // 2. degree
  k_deg<<<2048, 256, 0, stream>>>(dst, E, deg);
  // 3. dinv
  k_dinv<<<(N + 255) / 256, 256, 0, stream>>>(deg, dinv, N);
  // 4. scan
  k_scan<<<1, 1024, 0, stream>>>(deg, row_ptr, N);
  // 5. CSR fill
  k_fill<<<2048, 256, 0, stream>>>(src, dst, E, row_ptr, fill, ssrc);
  // 6. GEMM1 (+dinv scale)
  k_gemm<128><<<(N + 63) / 64, 256, 0, stream>>>(x, W1, dinv, h1, N);
  // 7. aggregate + bias + relu
  k_agg<128, true><<<(N + 3) / 4, 256, 0, stream>>>(h1, row_ptr, deg, ssrc, dinv,
                                                    b1, out1, N);
  // 8. GEMM2 (+dinv scale)
  k_gemm<64><<<(N + 63) / 64, 256, 0, stream>>>(out1, W2, dinv, h2, N);
  // 9. aggregate + bias
  k_agg<64, false><<<(N + 3) / 4, 256, 0, stream>>>(h2, row_ptr, deg, ssrc, dinv,
                                                    b2, out2, N);
  (void)n_in; (void)out_size; (void)NC2;
}

// Round 2
// 469.342 us; speedup vs baseline: 1.2990x; 1.2990x over previous
//
#include <hip/hip_runtime.h>

// ---------------------------------------------------------------------------
// 2-layer GCN on MI355X.
//   1. zero deg/fill
//   2. deg[d] = #edges with dst==d          (int atomics)
//   3. dinv[n] = rsqrt(deg[n]+1)            (+1 = self loop)
//   4. row_ptr = exclusive_scan(deg)        (3-phase multi-block scan)
//   5. CSR fill: ssrc sorted by dst         (int atomics for slots)
//   6. h1 = (x @ W1) * dinv[row]            (fp32 vector GEMM, K=128, NC=128)
//   7. out1 = relu(dinv[n]*(h1[n] + sum_{e->n} h1[src]) + b1)
//   8. h2 = (out1 @ W2) * dinv[row]         (K=128, NC=64)
//   9. d_out = dinv[n]*(h2[n] + sum h2[src]) + b2
// Normalization identity: sum_e h[src]*dinv[src]*dinv[dst]
//   = dinv[dst] * sum_e (h[src]*dinv[src])  -> fold dinv into GEMM epilogue.
// R1 fix: single-block scan was 160us @0.16% occupancy -> 3-phase scan.
// ---------------------------------------------------------------------------

__global__ void k_zero(int* __restrict__ p, int n) {
  int i = blockIdx.x * blockDim.x + threadIdx.x;
  int stride = gridDim.x * blockDim.x;
  for (; i < n; i += stride) p[i] = 0;
}

__global__ void k_deg(const int* __restrict__ dst, int E, int* __restrict__ deg) {
  int i = blockIdx.x * blockDim.x + threadIdx.x;
  int stride = gridDim.x * blockDim.x;
  for (; i < E; i += stride) atomicAdd(&deg[dst[i]], 1);
}

__global__ void k_dinv(const int* __restrict__ deg, float* __restrict__ dinv, int N) {
  int i = blockIdx.x * blockDim.x + threadIdx.x;
  if (i < N) dinv[i] = rsqrtf((float)(deg[i] + 1));
}

// ---- 3-phase exclusive scan: 256 thr x ITEMS elems per block ----
constexpr int SCAN_ITEMS = 8;  // 2048 elems / block

__global__ __launch_bounds__(256) void k_scan1(const int* __restrict__ deg, int N,
                                               int* __restrict__ bsum) {
  const int t = threadIdx.x;
  const int base = blockIdx.x * 256 * SCAN_ITEMS + t * SCAN_ITEMS;
  int s = 0;
#pragma unroll
  for (int i = 0; i < SCAN_ITEMS; ++i) {
    int idx = base + i;
    if (idx < N) s += deg[idx];
  }
  __shared__ int sm[256];
  sm[t] = s;
  __syncthreads();
  for (int off = 128; off > 0; off >>= 1) {
    if (t < off) sm[t] += sm[t + off];
    __syncthreads();
  }
  if (t == 0) bsum[blockIdx.x] = sm[0];
}

__global__ __launch_bounds__(1024) void k_scan2(int* __restrict__ bsum, int nb) {
  __shared__ int sm[1024];
  const int t = threadIdx.x;
  int v = (t < nb) ? bsum[t] : 0;
  sm[t] = v;
  __syncthreads();
  for (int off = 1; off < 1024; off <<= 1) {
    int add = (t >= off) ? sm[t - off] : 0;
    __syncthreads();
    sm[t] += add;
    __syncthreads();
  }
  if (t < nb) bsum[t] = sm[t] - v;  // exclusive
}

__global__ __launch_bounds__(256) void k_scan3(const int* __restrict__ deg, int N,
                                               const int* __restrict__ bsum,
                                               int* __restrict__ row_ptr) {
  const int t = threadIdx.x;
  const int base = blockIdx.x * 256 * SCAN_ITEMS + t * SCAN_ITEMS;
  int loc[SCAN_ITEMS];
  int s = 0;
#pragma unroll
  for (int i = 0; i < SCAN_ITEMS; ++i) {
    int idx = base + i;
    loc[i] = (idx < N) ? deg[idx] : 0;
    s += loc[i];
  }
  __shared__ int sm[256];
  sm[t] = s;
  __syncthreads();
  for (int off = 1; off < 256; off <<= 1) {
    int add = (t >= off) ? sm[t - off] : 0;
    __syncthreads();
    sm[t] += add;
    __syncthreads();
  }
  int run = bsum[blockIdx.x] + sm[t] - s;  // exclusive prefix for this thread
#pragma unroll
  for (int i = 0; i < SCAN_ITEMS; ++i) {
    int idx = base + i;
    if (idx < N) row_ptr[idx] = run;
    run += loc[i];
  }
}

__global__ void k_fill(const int* __restrict__ src, const int* __restrict__ dst, int E,
                       const int* __restrict__ row_ptr, int* __restrict__ fill,
                       int* __restrict__ ssrc) {
  int i = blockIdx.x * blockDim.x + threadIdx.x;
  int stride = gridDim.x * blockDim.x;
  for (; i < E; i += stride) {
    int d = dst[i];
    int pos = row_ptr[d] + atomicAdd(&fill[d], 1);
    ssrc[pos] = src[i];
  }
}

// H[row][c] = (sum_k X[row][k] * W[k][c]) * dinv[row].
// Block: 256 threads, 64 rows x NC cols. X staged transposed in LDS.
template <int NC>
__global__ __launch_bounds__(256) void k_gemm(const float* __restrict__ X,
                                              const float* __restrict__ W,
                                              const float* __restrict__ dinv,
                                              float* __restrict__ H, int N) {
  constexpr int K = 128;
  constexpr int BM = 64;
  constexpr int LDX = BM + 4;
  __shared__ float xs[K][LDX];
  const int t = threadIdx.x;
  const int r0 = blockIdx.x * BM;

  for (int idx = t; idx < BM * (K / 4); idx += 256) {
    int row = idx >> 5;
    int kg = idx & 31;
    float4 v = make_float4(0.f, 0.f, 0.f, 0.f);
    if (r0 + row < N)
      v = *reinterpret_cast<const float4*>(X + (size_t)(r0 + row) * K + 4 * kg);
    xs[4 * kg + 0][row] = v.x;
    xs[4 * kg + 1][row] = v.y;
    xs[4 * kg + 2][row] = v.z;
    xs[4 * kg + 3][row] = v.w;
  }
  __syncthreads();

  constexpr int CG = NC / 4;
  constexpr int RPT = BM / (256 / CG);
  const int tx = t % CG;
  const int ty = t / CG;

  float acc[RPT][4];
#pragma unroll
  for (int r = 0; r < RPT; ++r) {
    acc[r][0] = 0.f; acc[r][1] = 0.f; acc[r][2] = 0.f; acc[r][3] = 0.f;
  }

#pragma unroll 4
  for (int k = 0; k < K; ++k) {
    const float4 w4 = *reinterpret_cast<const float4*>(W + (size_t)k * NC + 4 * tx);
    const float4* xr = reinterpret_cast<const float4*>(&xs[k][ty * RPT]);
#pragma unroll
    for (int rq = 0; rq < RPT / 4; ++rq) {
      float4 xv = xr[rq];
      float xe[4] = {xv.x, xv.y, xv.z, xv.w};
#pragma unroll
      for (int j = 0; j < 4; ++j) {
        int r = rq * 4 + j;
        acc[r][0] += xe[j] * w4.x;
        acc[r][1] += xe[j] * w4.y;
        acc[r][2] += xe[j] * w4.z;
        acc[r][3] += xe[j] * w4.w;
      }
    }
  }

#pragma unroll
  for (int r = 0; r < RPT; ++r) {
    int row = r0 + ty * RPT + r;
    if (row < N) {
      float dv = dinv[row];
      float4 o = make_float4(acc[r][0] * dv, acc[r][1] * dv, acc[r][2] * dv,
                             acc[r][3] * dv);
      *reinterpret_cast<float4*>(H + (size_t)row * NC + 4 * tx) = o;
    }
  }
}

// One wave per node: acc = H[n] + sum_{e: dst==n} H[ssrc[e]];
// out[n] = maybe_relu(acc * dinv[n] + bias).
template <int C, bool RELU>
__global__ __launch_bounds__(256) void k_agg(const float* __restrict__ H,
                                             const int* __restrict__ row_ptr,
                                             const int* __restrict__ deg,
                                             const int* __restrict__ ssrc,
                                             const float* __restrict__ dinv,
                                             const float* __restrict__ bias,
                                             float* __restrict__ out, int N) {
  const int wave = threadIdx.x >> 6;
  const int lane = threadIdx.x & 63;
  const int n = blockIdx.x * 4 + wave;
  if (n >= N) return;

  const int e0 = row_ptr[n];
  const int e1 = e0 + deg[n];
  const float dv = dinv[n];

  if constexpr (C == 128) {
    float2 acc = *reinterpret_cast<const float2*>(H + (size_t)n * C + 2 * lane);
    int e = e0;
    for (; e + 4 <= e1; e += 4) {
      int s0 = ssrc[e], s1 = ssrc[e + 1], s2 = ssrc[e + 2], s3 = ssrc[e + 3];
      float2 v0 = *reinterpret_cast<const float2*>(H + (size_t)s0 * C + 2 * lane);
      float2 v1 = *reinterpret_cast<const float2*>(H + (size_t)s1 * C + 2 * lane);
      float2 v2 = *reinterpret_cast<const float2*>(H + (size_t)s2 * C + 2 * lane);
      float2 v3 = *reinterpret_cast<const float2*>(H + (size_t)s3 * C + 2 * lane);
      acc.x += (v0.x + v1.x) + (v2.x + v3.x);
      acc.y += (v0.y + v1.y) + (v2.y + v3.y);
    }
    for (; e < e1; ++e) {
      int s = ssrc[e];
      float2 v = *reinterpret_cast<const float2*>(H + (size_t)s * C + 2 * lane);
      acc.x += v.x;
      acc.y += v.y;
    }
    float2 b = *reinterpret_cast<const float2*>(bias + 2 * lane);
    float ox = acc.x * dv + b.x;
    float oy = acc.y * dv + b.y;
    if (RELU) { ox = fmaxf(ox, 0.f); oy = fmaxf(oy, 0.f); }
    *reinterpret_cast<float2*>(out + (size_t)n * C + 2 * lane) = make_float2(ox, oy);
  } else {  // C == 64
    float acc = H[(size_t)n * C + lane];
    int e = e0;
    for (; e + 4 <= e1; e += 4) {
      int s0 = ssrc[e], s1 = ssrc[e + 1], s2 = ssrc[e + 2], s3 = ssrc[e + 3];
      float v0 = H[(size_t)s0 * C + lane];
      float v1 = H[(size_t)s1 * C + lane];
      float v2 = H[(size_t)s2 * C + lane];
      float v3 = H[(size_t)s3 * C + lane];
      acc += (v0 + v1) + (v2 + v3);
    }
    for (; e < e1; ++e) {
      int s = ssrc[e];
      acc += H[(size_t)s * C + lane];
    }
    float o = acc * dv + bias[lane];
    if (RELU) o = fmaxf(o, 0.f);
    out[(size_t)n * C + lane] = o;
  }
}

extern "C" void kernel_launch(void* const* d_in, const int* in_sizes, int n_in,
                              void* d_out, int out_size, void* d_ws, size_t ws_size,
                              hipStream_t stream) {
  const float* x = (const float*)d_in[0];
  const int* ei = (const int*)d_in[1];
  const float* W1 = (const float*)d_in[2];
  const float* b1 = (const float*)d_in[3];
  const float* W2 = (const float*)d_in[4];
  const float* b2 = (const float*)d_in[5];

  const int K = 128;
  const int N = in_sizes[0] / K;     // 100000
  const int E = in_sizes[1] / 2;     // 1600000

  const int* src = ei;
  const int* dst = ei + E;

  size_t off = 0;
  auto carve = [&](size_t bytes) {
    size_t o = off;
    off += (bytes + 255) & ~(size_t)255;
    return o;
  };
  char* ws = (char*)d_ws;
  int*   deg     = (int*)(ws + carve((size_t)N * 4));
  int*   row_ptr = (int*)(ws + carve((size_t)N * 4));
  int*   fill    = (int*)(ws + carve((size_t)N * 4));
  float* dinv    = (float*)(ws + carve((size_t)N * 4));
  int*   bsum    = (int*)(ws + carve(1024 * 4));
  int*   ssrc    = (int*)(ws + carve((size_t)E * 4));
  float* h1      = (float*)(ws + carve((size_t)N * K * 4));   // reused as h2
  float* out1    = (float*)(ws + carve((size_t)N * K * 4));
  if (off > ws_size) return;

  float* h2 = h1;  // h1 dead after agg1
  float* out2 = (float*)d_out;

  const int elems_per_blk = 256 * SCAN_ITEMS;          // 2048
  const int nb = (N + elems_per_blk - 1) / elems_per_blk;  // 49

  k_zero<<<(N + 255) / 256, 256, 0, stream>>>(deg, N);
  k_zero<<<(N + 255) / 256, 256, 0, stream>>>(fill, N);
  k_deg<<<2048, 256, 0, stream>>>(dst, E, deg);
  k_dinv<<<(N + 255) / 256, 256, 0, stream>>>(deg, dinv, N);
  k_scan1<<<nb, 256, 0, stream>>>(deg, N, bsum);
  k_scan2<<<1, 1024, 0, stream>>>(bsum, nb);
  k_scan3<<<nb, 256, 0, stream>>>(deg, N, bsum, row_ptr);
  k_fill<<<2048, 256, 0, stream>>>(src, dst, E, row_ptr, fill, ssrc);
  k_gemm<128><<<(N + 63) / 64, 256, 0, stream>>>(x, W1, dinv, h1, N);
  k_agg<128, true><<<(N + 3) / 4, 256, 0, stream>>>(h1, row_ptr, deg, ssrc, dinv,
                                                    b1, out1, N);
  k_gemm<64><<<(N + 63) / 64, 256, 0, stream>>>(out1, W2, dinv, h2, N);
  k_agg<64, false><<<(N + 3) / 4, 256, 0, stream>>>(h2, row_ptr, deg, ssrc, dinv,
                                                    b2, out2, N);
  (void)n_in; (void)out_size;
}

// Round 3
// 387.626 us; speedup vs baseline: 1.5729x; 1.2108x over previous
//
#include <hip/hip_runtime.h>
#include <hip/hip_fp16.h>

// ---------------------------------------------------------------------------
// 2-layer GCN on MI355X.
//   deg/scan/fill build CSR (dst-sorted src list) each launch.
//   h = (x @ W) * dinv[row] stored FP16 (halves gather traffic),
//   agg: out[n] = maybe_relu(dinv[n]*(h[n] + sum_{e->n} h[src]) + b)
// R1: 3-phase scan (was 160us single-block).
// R2: h stored fp16; agg processes 2 edges/instr via 32-lane groups
//     (gather bytes halve: layer1 512->256B/edge, layer2 256->128B/edge).
// ---------------------------------------------------------------------------

__global__ void k_zero2(int* __restrict__ a, int* __restrict__ b, int n) {
  int i = blockIdx.x * blockDim.x + threadIdx.x;
  int stride = gridDim.x * blockDim.x;
  for (; i < n; i += stride) { a[i] = 0; b[i] = 0; }
}

__global__ void k_deg(const int* __restrict__ dst, int E, int* __restrict__ deg) {
  int i = blockIdx.x * blockDim.x + threadIdx.x;
  int stride = gridDim.x * blockDim.x;
  for (; i < E; i += stride) atomicAdd(&deg[dst[i]], 1);
}

__global__ void k_dinv(const int* __restrict__ deg, float* __restrict__ dinv, int N) {
  int i = blockIdx.x * blockDim.x + threadIdx.x;
  if (i < N) dinv[i] = rsqrtf((float)(deg[i] + 1));
}

// ---- 3-phase exclusive scan ----
constexpr int SCAN_ITEMS = 8;  // 2048 elems / block

__global__ __launch_bounds__(256) void k_scan1(const int* __restrict__ deg, int N,
                                               int* __restrict__ bsum) {
  const int t = threadIdx.x;
  const int base = blockIdx.x * 256 * SCAN_ITEMS + t * SCAN_ITEMS;
  int s = 0;
#pragma unroll
  for (int i = 0; i < SCAN_ITEMS; ++i) {
    int idx = base + i;
    if (idx < N) s += deg[idx];
  }
  __shared__ int sm[256];
  sm[t] = s;
  __syncthreads();
  for (int off = 128; off > 0; off >>= 1) {
    if (t < off) sm[t] += sm[t + off];
    __syncthreads();
  }
  if (t == 0) bsum[blockIdx.x] = sm[0];
}

__global__ __launch_bounds__(1024) void k_scan2(int* __restrict__ bsum, int nb) {
  __shared__ int sm[1024];
  const int t = threadIdx.x;
  int v = (t < nb) ? bsum[t] : 0;
  sm[t] = v;
  __syncthreads();
  for (int off = 1; off < 1024; off <<= 1) {
    int add = (t >= off) ? sm[t - off] : 0;
    __syncthreads();
    sm[t] += add;
    __syncthreads();
  }
  if (t < nb) bsum[t] = sm[t] - v;  // exclusive
}

__global__ __launch_bounds__(256) void k_scan3(const int* __restrict__ deg, int N,
                                               const int* __restrict__ bsum,
                                               int* __restrict__ row_ptr) {
  const int t = threadIdx.x;
  const int base = blockIdx.x * 256 * SCAN_ITEMS + t * SCAN_ITEMS;
  int loc[SCAN_ITEMS];
  int s = 0;
#pragma unroll
  for (int i = 0; i < SCAN_ITEMS; ++i) {
    int idx = base + i;
    loc[i] = (idx < N) ? deg[idx] : 0;
    s += loc[i];
  }
  __shared__ int sm[256];
  sm[t] = s;
  __syncthreads();
  for (int off = 1; off < 256; off <<= 1) {
    int add = (t >= off) ? sm[t - off] : 0;
    __syncthreads();
    sm[t] += add;
    __syncthreads();
  }
  int run = bsum[blockIdx.x] + sm[t] - s;
#pragma unroll
  for (int i = 0; i < SCAN_ITEMS; ++i) {
    int idx = base + i;
    if (idx < N) row_ptr[idx] = run;
    run += loc[i];
  }
}

__global__ void k_fill(const int* __restrict__ src, const int* __restrict__ dst, int E,
                       const int* __restrict__ row_ptr, int* __restrict__ fill,
                       int* __restrict__ ssrc) {
  int i = blockIdx.x * blockDim.x + threadIdx.x;
  int stride = gridDim.x * blockDim.x;
  for (; i < E; i += stride) {
    int d = dst[i];
    int pos = row_ptr[d] + atomicAdd(&fill[d], 1);
    ssrc[pos] = src[i];
  }
}

// H[row][c] = (sum_k X[row][k] * W[k][c]) * dinv[row], stored fp16.
template <int NC>
__global__ __launch_bounds__(256) void k_gemm(const float* __restrict__ X,
                                              const float* __restrict__ W,
                                              const float* __restrict__ dinv,
                                              __half* __restrict__ H, int N) {
  constexpr int K = 128;
  constexpr int BM = 64;
  constexpr int LDX = BM + 4;
  __shared__ float xs[K][LDX];
  const int t = threadIdx.x;
  const int r0 = blockIdx.x * BM;

  for (int idx = t; idx < BM * (K / 4); idx += 256) {
    int row = idx >> 5;
    int kg = idx & 31;
    float4 v = make_float4(0.f, 0.f, 0.f, 0.f);
    if (r0 + row < N)
      v = *reinterpret_cast<const float4*>(X + (size_t)(r0 + row) * K + 4 * kg);
    xs[4 * kg + 0][row] = v.x;
    xs[4 * kg + 1][row] = v.y;
    xs[4 * kg + 2][row] = v.z;
    xs[4 * kg + 3][row] = v.w;
  }
  __syncthreads();

  constexpr int CG = NC / 4;
  constexpr int RPT = BM / (256 / CG);
  const int tx = t % CG;
  const int ty = t / CG;

  float acc[RPT][4];
#pragma unroll
  for (int r = 0; r < RPT; ++r) {
    acc[r][0] = 0.f; acc[r][1] = 0.f; acc[r][2] = 0.f; acc[r][3] = 0.f;
  }

#pragma unroll 4
  for (int k = 0; k < K; ++k) {
    const float4 w4 = *reinterpret_cast<const float4*>(W + (size_t)k * NC + 4 * tx);
    const float4* xr = reinterpret_cast<const float4*>(&xs[k][ty * RPT]);
#pragma unroll
    for (int rq = 0; rq < RPT / 4; ++rq) {
      float4 xv = xr[rq];
      float xe[4] = {xv.x, xv.y, xv.z, xv.w};
#pragma unroll
      for (int j = 0; j < 4; ++j) {
        int r = rq * 4 + j;
        acc[r][0] += xe[j] * w4.x;
        acc[r][1] += xe[j] * w4.y;
        acc[r][2] += xe[j] * w4.z;
        acc[r][3] += xe[j] * w4.w;
      }
    }
  }

#pragma unroll
  for (int r = 0; r < RPT; ++r) {
    int row = r0 + ty * RPT + r;
    if (row < N) {
      float dv = dinv[row];
      __half2 p01 = __float22half2_rn(make_float2(acc[r][0] * dv, acc[r][1] * dv));
      __half2 p23 = __float22half2_rn(make_float2(acc[r][2] * dv, acc[r][3] * dv));
      float2 packed;
      *reinterpret_cast<__half2*>(&packed.x) = p01;
      *reinterpret_cast<__half2*>(&packed.y) = p23;
      *reinterpret_cast<float2*>(H + (size_t)row * NC + 4 * tx) = packed;
    }
  }
}

// One wave per node; 2 edges per load instruction via 32-lane groups.
// Group eh = lane>>5 handles edges e+2i+eh; final __shfl_xor(32) combine.
template <int C, bool RELU>
__global__ __launch_bounds__(256) void k_agg(const __half* __restrict__ H,
                                             const int* __restrict__ row_ptr,
                                             const int* __restrict__ deg,
                                             const int* __restrict__ ssrc,
                                             const float* __restrict__ dinv,
                                             const float* __restrict__ bias,
                                             float* __restrict__ out, int N) {
  const int wave = threadIdx.x >> 6;
  const int lane = threadIdx.x & 63;
  const int n = blockIdx.x * 4 + wave;
  if (n >= N) return;

  const int eh = lane >> 5;   // edge-slot within pair
  const int cl = lane & 31;   // column-group within row
  const int e0 = row_ptr[n];
  const int e1 = e0 + deg[n];
  const float dv = dinv[n];

  if constexpr (C == 128) {
    // each lane: 4 cols (4*cl .. 4*cl+3), 8B fp16 load per edge-row
    float4 acc = make_float4(0.f, 0.f, 0.f, 0.f);
    auto gat = [&](int s) {
      float2 raw = *reinterpret_cast<const float2*>(H + (size_t)s * C + 4 * cl);
      float2 f01 = __half22float2(*reinterpret_cast<__half2*>(&raw.x));
      float2 f23 = __half22float2(*reinterpret_cast<__half2*>(&raw.y));
      acc.x += f01.x; acc.y += f01.y; acc.z += f23.x; acc.w += f23.y;
    };
    if (eh == 0) gat(n);  // self-loop in group 0 only
    int e = e0;
    for (; e + 8 <= e1; e += 8) {
      int s0 = ssrc[e + eh];
      int s1 = ssrc[e + 2 + eh];
      int s2 = ssrc[e + 4 + eh];
      int s3 = ssrc[e + 6 + eh];
      gat(s0); gat(s1); gat(s2); gat(s3);
    }
    for (; e + 2 <= e1; e += 2) gat(ssrc[e + eh]);
    if (e < e1 && eh == 0) gat(ssrc[e]);
    // combine the two edge-groups
    acc.x += __shfl_xor(acc.x, 32);
    acc.y += __shfl_xor(acc.y, 32);
    acc.z += __shfl_xor(acc.z, 32);
    acc.w += __shfl_xor(acc.w, 32);
    if (eh == 0) {
      float4 b = *reinterpret_cast<const float4*>(bias + 4 * cl);
      float4 o = make_float4(acc.x * dv + b.x, acc.y * dv + b.y,
                             acc.z * dv + b.z, acc.w * dv + b.w);
      if (RELU) {
        o.x = fmaxf(o.x, 0.f); o.y = fmaxf(o.y, 0.f);
        o.z = fmaxf(o.z, 0.f); o.w = fmaxf(o.w, 0.f);
      }
      *reinterpret_cast<float4*>(out + (size_t)n * C + 4 * cl) = o;
    }
  } else {  // C == 64: each lane 2 cols (2*cl..2*cl+1), 4B fp16 load
    float2 acc = make_float2(0.f, 0.f);
    auto gat = [&](int s) {
      __half2 h01 = *reinterpret_cast<const __half2*>(H + (size_t)s * C + 2 * cl);
      float2 f = __half22float2(h01);
      acc.x += f.x; acc.y += f.y;
    };
    if (eh == 0) gat(n);
    int e = e0;
    for (; e + 8 <= e1; e += 8) {
      int s0 = ssrc[e + eh];
      int s1 = ssrc[e + 2 + eh];
      int s2 = ssrc[e + 4 + eh];
      int s3 = ssrc[e + 6 + eh];
      gat(s0); gat(s1); gat(s2); gat(s3);
    }
    for (; e + 2 <= e1; e += 2) gat(ssrc[e + eh]);
    if (e < e1 && eh == 0) gat(ssrc[e]);
    acc.x += __shfl_xor(acc.x, 32);
    acc.y += __shfl_xor(acc.y, 32);
    if (eh == 0) {
      float2 b = *reinterpret_cast<const float2*>(bias + 2 * cl);
      float ox = acc.x * dv + b.x;
      float oy = acc.y * dv + b.y;
      if (RELU) { ox = fmaxf(ox, 0.f); oy = fmaxf(oy, 0.f); }
      *reinterpret_cast<float2*>(out + (size_t)n * C + 2 * cl) = make_float2(ox, oy);
    }
  }
}

extern "C" void kernel_launch(void* const* d_in, const int* in_sizes, int n_in,
                              void* d_out, int out_size, void* d_ws, size_t ws_size,
                              hipStream_t stream) {
  const float* x = (const float*)d_in[0];
  const int* ei = (const int*)d_in[1];
  const float* W1 = (const float*)d_in[2];
  const float* b1 = (const float*)d_in[3];
  const float* W2 = (const float*)d_in[4];
  const float* b2 = (const float*)d_in[5];

  const int K = 128;
  const int N = in_sizes[0] / K;     // 100000
  const int E = in_sizes[1] / 2;     // 1600000

  const int* src = ei;
  const int* dst = ei + E;

  size_t off = 0;
  auto carve = [&](size_t bytes) {
    size_t o = off;
    off += (bytes + 255) & ~(size_t)255;
    return o;
  };
  char* ws = (char*)d_ws;
  int*    deg     = (int*)(ws + carve((size_t)N * 4));
  int*    row_ptr = (int*)(ws + carve((size_t)N * 4));
  int*    fill    = (int*)(ws + carve((size_t)N * 4));
  float*  dinv    = (float*)(ws + carve((size_t)N * 4));
  int*    bsum    = (int*)(ws + carve(1024 * 4));
  int*    ssrc    = (int*)(ws + carve((size_t)E * 4));
  __half* h1      = (__half*)(ws + carve((size_t)N * K * 2));  // fp16, reused as h2
  float*  out1    = (float*)(ws + carve((size_t)N * K * 4));
  if (off > ws_size) return;

  __half* h2 = h1;
  float* out2 = (float*)d_out;

  const int elems_per_blk = 256 * SCAN_ITEMS;
  const int nb = (N + elems_per_blk - 1) / elems_per_blk;

  k_zero2<<<(N + 255) / 256, 256, 0, stream>>>(deg, fill, N);
  k_deg<<<2048, 256, 0, stream>>>(dst, E, deg);
  k_dinv<<<(N + 255) / 256, 256, 0, stream>>>(deg, dinv, N);
  k_scan1<<<nb, 256, 0, stream>>>(deg, N, bsum);
  k_scan2<<<1, 1024, 0, stream>>>(bsum, nb);
  k_scan3<<<nb, 256, 0, stream>>>(deg, N, bsum, row_ptr);
  k_fill<<<2048, 256, 0, stream>>>(src, dst, E, row_ptr, fill, ssrc);
  k_gemm<128><<<(N + 63) / 64, 256, 0, stream>>>(x, W1, dinv, h1, N);
  k_agg<128, true><<<(N + 3) / 4, 256, 0, stream>>>(h1, row_ptr, deg, ssrc, dinv,
                                                    b1, out1, N);
  k_gemm<64><<<(N + 63) / 64, 256, 0, stream>>>(out1, W2, dinv, h2, N);
  k_agg<64, false><<<(N + 3) / 4, 256, 0, stream>>>(h2, row_ptr, deg, ssrc, dinv,
                                                    b2, out2, N);
  (void)n_in; (void)out_size;
}

// Round 4
// 257.658 us; speedup vs baseline: 2.3663x; 1.5044x over previous
//
#include <hip/hip_runtime.h>
#include <hip/hip_fp16.h>

// ---------------------------------------------------------------------------
// 2-layer GCN on MI355X.
// R1: 3-phase scan replaced 160us single-block scan.
// R2: h stored fp16 (halves gather traffic); agg: 2 edges per load via
//     32-lane groups.
// R3->R4: CSR build rewritten as two-level LDS counting sort. Old k_fill did
//     1.6M random 4B global writes -> 108MB HBM write traffic (every store
//     dirtied a line that bounced across XCD L2s) + k_deg's 1.6M contended
//     atomics. New scheme: block-local LDS sort into 782 coarse buckets
//     (coalesced run writes, 1 atomic per block*bucket), then per-bucket LDS
//     histogram (deg/row_ptr/dinv with zero global atomics) + scatter into an
//     8KB window.
// ---------------------------------------------------------------------------

constexpr int BK_SHIFT = 7;               // 128 nodes per bucket
constexpr int BK_NODES = 1 << BK_SHIFT;
constexpr int NB_MAX   = 1024;            // max buckets (N up to 131072)
constexpr int SLAB     = 2560;            // slots per bucket slab (mean 2046 + 11 sigma)
constexpr int P1_EPT   = 32;              // edges per thread in pass 1
constexpr int P1_EDGES = 256 * P1_EPT;    // 8192 per block

// ---- pass 1: LDS counting sort of 8192 edges into coarse buckets ----
__global__ __launch_bounds__(256) void k_p1(const int* __restrict__ src,
                                            const int* __restrict__ dst, int E,
                                            int NB, int* __restrict__ bfill,
                                            unsigned* __restrict__ slab) {
  __shared__ unsigned stage[P1_EDGES];
  __shared__ unsigned short bidp[P1_EDGES];
  __shared__ int hist[NB_MAX];
  __shared__ int lbase[NB_MAX];   // exclusive prefix, then reused as cursor
  __shared__ int goff[NB_MAX];
  __shared__ int part[256];

  const int t = threadIdx.x;
  const long base = (long)blockIdx.x * P1_EDGES;
  const int nval = (int)(((long)E - base < (long)P1_EDGES) ? (E - base) : P1_EDGES);

  for (int i = t; i < NB; i += 256) hist[i] = 0;
  __syncthreads();

  int eb[P1_EPT];
  unsigned ev[P1_EPT];
#pragma unroll
  for (int i = 0; i < P1_EPT; ++i) {
    long e = base + t + i * 256;
    int b = -1;
    unsigned v = 0;
    if (e < E) {
      int d = dst[e];
      int s = src[e];
      b = d >> BK_SHIFT;
      v = ((unsigned)(d & (BK_NODES - 1)) << 17) | (unsigned)s;
      atomicAdd(&hist[b], 1);
    }
    eb[i] = b;
    ev[i] = v;
  }
  __syncthreads();

  // exclusive scan of hist[0..NB) -> lbase (4 buckets per thread)
  int lc[4];
  int lsum = 0;
#pragma unroll
  for (int j = 0; j < 4; ++j) {
    int b = t * 4 + j;
    lc[j] = (b < NB) ? hist[b] : 0;
    lsum += lc[j];
  }
  part[t] = lsum;
  __syncthreads();
  for (int o = 1; o < 256; o <<= 1) {
    int a = (t >= o) ? part[t - o] : 0;
    __syncthreads();
    part[t] += a;
    __syncthreads();
  }
  int run = part[t] - lsum;
#pragma unroll
  for (int j = 0; j < 4; ++j) {
    int b = t * 4 + j;
    if (b < NB) lbase[b] = run;
    run += lc[j];
  }
  __syncthreads();

  // reserve a contiguous run per non-empty bucket; goff maps staging pos -> slab pos
  for (int b = t; b < NB; b += 256) {
    int len = hist[b];
    int g = len ? atomicAdd(&bfill[b], len) : 0;
    goff[b] = b * SLAB + g - lbase[b];
  }
  __syncthreads();

  // scatter into LDS staging, sorted by bucket (lbase reused as cursor)
#pragma unroll
  for (int i = 0; i < P1_EPT; ++i) {
    if (eb[i] >= 0) {
      int p = atomicAdd(&lbase[eb[i]], 1);
      stage[p] = ev[i];
      bidp[p] = (unsigned short)eb[i];
    }
  }
  __syncthreads();

  // coalesced copy-out: consecutive staging positions within a bucket map to
  // consecutive slab positions
  for (int p = t; p < nval; p += 256) {
    int b = bidp[p];
    slab[goff[b] + p] = stage[p];
  }
}

// ---- scan of bucket counts -> bucket base offsets ----
__global__ __launch_bounds__(1024) void k_bscan(const int* __restrict__ bfill, int NB,
                                                int* __restrict__ bbase) {
  __shared__ int sm[1024];
  const int t = threadIdx.x;
  int v = (t < NB) ? bfill[t] : 0;
  sm[t] = v;
  __syncthreads();
  for (int o = 1; o < 1024; o <<= 1) {
    int a = (t >= o) ? sm[t - o] : 0;
    __syncthreads();
    sm[t] += a;
    __syncthreads();
  }
  if (t < NB) bbase[t] = sm[t] - v;  // exclusive
}

// ---- pass 2: per-bucket fine CSR (deg/row_ptr/dinv + ssrc) ----
__global__ __launch_bounds__(256) void k_p2(const unsigned* __restrict__ slab,
                                            const int* __restrict__ bfill,
                                            const int* __restrict__ bbase, int N,
                                            int* __restrict__ deg,
                                            int* __restrict__ row_ptr,
                                            float* __restrict__ dinv,
                                            int* __restrict__ ssrc) {
  __shared__ int hist[BK_NODES];
  __shared__ int lb[BK_NODES];
  const int b = blockIdx.x;
  const int t = threadIdx.x;
  const int len = bfill[b];
  const int gbase = bbase[b];
  const unsigned* seg = slab + (size_t)b * SLAB;

  if (t < BK_NODES) hist[t] = 0;
  __syncthreads();
  for (int i = t; i < len; i += 256) atomicAdd(&hist[seg[i] >> 17], 1);
  __syncthreads();

  // inclusive scan over 128 node counts
  if (t < BK_NODES) lb[t] = hist[t];
  __syncthreads();
  for (int o = 1; o < BK_NODES; o <<= 1) {
    int a = 0;
    if (t < BK_NODES && t >= o) a = lb[t - o];
    __syncthreads();
    if (t < BK_NODES) lb[t] += a;
    __syncthreads();
  }

  int n = b * BK_NODES + t;
  if (t < BK_NODES && n < N) {
    int d = hist[t];
    deg[n] = d;
    row_ptr[n] = gbase + lb[t] - d;
    dinv[n] = rsqrtf((float)(d + 1));
  }
  __syncthreads();
  if (t < BK_NODES) lb[t] -= hist[t];  // cursor = exclusive prefix
  __syncthreads();

  for (int i = t; i < len; i += 256) {
    unsigned v = seg[i];
    int l = v >> 17;
    int p = atomicAdd(&lb[l], 1);
    ssrc[gbase + p] = (int)(v & 0x1FFFF);
  }
}

// ---- H[row][c] = (sum_k X[row][k] * W[k][c]) * dinv[row], stored fp16 ----
template <int NC>
__global__ __launch_bounds__(256) void k_gemm(const float* __restrict__ X,
                                              const float* __restrict__ W,
                                              const float* __restrict__ dinv,
                                              __half* __restrict__ H, int N) {
  constexpr int K = 128;
  constexpr int BM = 64;
  constexpr int LDX = BM + 4;
  __shared__ float xs[K][LDX];
  const int t = threadIdx.x;
  const int r0 = blockIdx.x * BM;

  for (int idx = t; idx < BM * (K / 4); idx += 256) {
    int row = idx >> 5;
    int kg = idx & 31;
    float4 v = make_float4(0.f, 0.f, 0.f, 0.f);
    if (r0 + row < N)
      v = *reinterpret_cast<const float4*>(X + (size_t)(r0 + row) * K + 4 * kg);
    xs[4 * kg + 0][row] = v.x;
    xs[4 * kg + 1][row] = v.y;
    xs[4 * kg + 2][row] = v.z;
    xs[4 * kg + 3][row] = v.w;
  }
  __syncthreads();

  constexpr int CG = NC / 4;
  constexpr int RPT = BM / (256 / CG);
  const int tx = t % CG;
  const int ty = t / CG;

  float acc[RPT][4];
#pragma unroll
  for (int r = 0; r < RPT; ++r) {
    acc[r][0] = 0.f; acc[r][1] = 0.f; acc[r][2] = 0.f; acc[r][3] = 0.f;
  }

#pragma unroll 4
  for (int k = 0; k < K; ++k) {
    const float4 w4 = *reinterpret_cast<const float4*>(W + (size_t)k * NC + 4 * tx);
    const float4* xr = reinterpret_cast<const float4*>(&xs[k][ty * RPT]);
#pragma unroll
    for (int rq = 0; rq < RPT / 4; ++rq) {
      float4 xv = xr[rq];
      float xe[4] = {xv.x, xv.y, xv.z, xv.w};
#pragma unroll
      for (int j = 0; j < 4; ++j) {
        int r = rq * 4 + j;
        acc[r][0] += xe[j] * w4.x;
        acc[r][1] += xe[j] * w4.y;
        acc[r][2] += xe[j] * w4.z;
        acc[r][3] += xe[j] * w4.w;
      }
    }
  }

#pragma unroll
  for (int r = 0; r < RPT; ++r) {
    int row = r0 + ty * RPT + r;
    if (row < N) {
      float dv = dinv[row];
      __half2 p01 = __float22half2_rn(make_float2(acc[r][0] * dv, acc[r][1] * dv));
      __half2 p23 = __float22half2_rn(make_float2(acc[r][2] * dv, acc[r][3] * dv));
      float2 packed;
      *reinterpret_cast<__half2*>(&packed.x) = p01;
      *reinterpret_cast<__half2*>(&packed.y) = p23;
      *reinterpret_cast<float2*>(H + (size_t)row * NC + 4 * tx) = packed;
    }
  }
}

// ---- aggregation: one wave per node, 2 edges per load via 32-lane groups ----
template <int C, bool RELU>
__global__ __launch_bounds__(256) void k_agg(const __half* __restrict__ H,
                                             const int* __restrict__ row_ptr,
                                             const int* __restrict__ deg,
                                             const int* __restrict__ ssrc,
                                             const float* __restrict__ dinv,
                                             const float* __restrict__ bias,
                                             float* __restrict__ out, int N) {
  const int wave = threadIdx.x >> 6;
  const int lane = threadIdx.x & 63;
  const int n = blockIdx.x * 4 + wave;
  if (n >= N) return;

  const int eh = lane >> 5;
  const int cl = lane & 31;
  const int e0 = row_ptr[n];
  const int e1 = e0 + deg[n];
  const float dv = dinv[n];

  if constexpr (C == 128) {
    float4 acc = make_float4(0.f, 0.f, 0.f, 0.f);
    auto gat = [&](int s) {
      float2 raw = *reinterpret_cast<const float2*>(H + (size_t)s * C + 4 * cl);
      float2 f01 = __half22float2(*reinterpret_cast<__half2*>(&raw.x));
      float2 f23 = __half22float2(*reinterpret_cast<__half2*>(&raw.y));
      acc.x += f01.x; acc.y += f01.y; acc.z += f23.x; acc.w += f23.y;
    };
    if (eh == 0) gat(n);
    int e = e0;
    for (; e + 8 <= e1; e += 8) {
      int s0 = ssrc[e + eh];
      int s1 = ssrc[e + 2 + eh];
      int s2 = ssrc[e + 4 + eh];
      int s3 = ssrc[e + 6 + eh];
      gat(s0); gat(s1); gat(s2); gat(s3);
    }
    for (; e + 2 <= e1; e += 2) gat(ssrc[e + eh]);
    if (e < e1 && eh == 0) gat(ssrc[e]);
    acc.x += __shfl_xor(acc.x, 32);
    acc.y += __shfl_xor(acc.y, 32);
    acc.z += __shfl_xor(acc.z, 32);
    acc.w += __shfl_xor(acc.w, 32);
    if (eh == 0) {
      float4 b = *reinterpret_cast<const float4*>(bias + 4 * cl);
      float4 o = make_float4(acc.x * dv + b.x, acc.y * dv + b.y,
                             acc.z * dv + b.z, acc.w * dv + b.w);
      if (RELU) {
        o.x = fmaxf(o.x, 0.f); o.y = fmaxf(o.y, 0.f);
        o.z = fmaxf(o.z, 0.f); o.w = fmaxf(o.w, 0.f);
      }
      *reinterpret_cast<float4*>(out + (size_t)n * C + 4 * cl) = o;
    }
  } else {  // C == 64
    float2 acc = make_float2(0.f, 0.f);
    auto gat = [&](int s) {
      __half2 h01 = *reinterpret_cast<const __half2*>(H + (size_t)s * C + 2 * cl);
      float2 f = __half22float2(h01);
      acc.x += f.x; acc.y += f.y;
    };
    if (eh == 0) gat(n);
    int e = e0;
    for (; e + 8 <= e1; e += 8) {
      int s0 = ssrc[e + eh];
      int s1 = ssrc[e + 2 + eh];
      int s2 = ssrc[e + 4 + eh];
      int s3 = ssrc[e + 6 + eh];
      gat(s0); gat(s1); gat(s2); gat(s3);
    }
    for (; e + 2 <= e1; e += 2) gat(ssrc[e + eh]);
    if (e < e1 && eh == 0) gat(ssrc[e]);
    acc.x += __shfl_xor(acc.x, 32);
    acc.y += __shfl_xor(acc.y, 32);
    if (eh == 0) {
      float2 b = *reinterpret_cast<const float2*>(bias + 2 * cl);
      float ox = acc.x * dv + b.x;
      float oy = acc.y * dv + b.y;
      if (RELU) { ox = fmaxf(ox, 0.f); oy = fmaxf(oy, 0.f); }
      *reinterpret_cast<float2*>(out + (size_t)n * C + 2 * cl) = make_float2(ox, oy);
    }
  }
}

extern "C" void kernel_launch(void* const* d_in, const int* in_sizes, int n_in,
                              void* d_out, int out_size, void* d_ws, size_t ws_size,
                              hipStream_t stream) {
  const float* x = (const float*)d_in[0];
  const int* ei = (const int*)d_in[1];
  const float* W1 = (const float*)d_in[2];
  const float* b1 = (const float*)d_in[3];
  const float* W2 = (const float*)d_in[4];
  const float* b2 = (const float*)d_in[5];

  const int K = 128;
  const int N = in_sizes[0] / K;     // 100000
  const int E = in_sizes[1] / 2;     // 1600000
  const int NB = (N + BK_NODES - 1) >> BK_SHIFT;  // 782
  if (NB > NB_MAX) return;

  const int* src = ei;
  const int* dst = ei + E;

  size_t off = 0;
  auto carve = [&](size_t bytes) {
    size_t o = off;
    off += (bytes + 255) & ~(size_t)255;
    return o;
  };
  char* ws = (char*)d_ws;
  int*      deg     = (int*)(ws + carve((size_t)N * 4));
  int*      row_ptr = (int*)(ws + carve((size_t)N * 4));
  float*    dinv    = (float*)(ws + carve((size_t)N * 4));
  int*      bfill   = (int*)(ws + carve((size_t)NB * 4));
  int*      bbase   = (int*)(ws + carve((size_t)NB * 4));
  unsigned* slab    = (unsigned*)(ws + carve((size_t)NB * SLAB * 4));
  int*      ssrc    = (int*)(ws + carve((size_t)E * 4));
  __half*   h1      = (__half*)(ws + carve((size_t)N * K * 2));  // reused as h2
  float*    out1    = (float*)(ws + carve((size_t)N * K * 4));
  if (off > ws_size) return;

  __half* h2 = h1;
  float* out2 = (float*)d_out;

  hipMemsetAsync(bfill, 0, (size_t)NB * 4, stream);
  const int nwg1 = (E + P1_EDGES - 1) / P1_EDGES;
  k_p1<<<nwg1, 256, 0, stream>>>(src, dst, E, NB, bfill, slab);
  k_bscan<<<1, 1024, 0, stream>>>(bfill, NB, bbase);
  k_p2<<<NB, 256, 0, stream>>>(slab, bfill, bbase, N, deg, row_ptr, dinv, ssrc);

  k_gemm<128><<<(N + 63) / 64, 256, 0, stream>>>(x, W1, dinv, h1, N);
  k_agg<128, true><<<(N + 3) / 4, 256, 0, stream>>>(h1, row_ptr, deg, ssrc, dinv,
                                                    b1, out1, N);
  k_gemm<64><<<(N + 63) / 64, 256, 0, stream>>>(out1, W2, dinv, h2, N);
  k_agg<64, false><<<(N + 3) / 4, 256, 0, stream>>>(h2, row_ptr, deg, ssrc, dinv,
                                                    b2, out2, N);
  (void)n_in; (void)out_size;
}

// Round 5
// 207.581 us; speedup vs baseline: 2.9371x; 1.2412x over previous
//
#include <hip/hip_runtime.h>
#include <hip/hip_fp16.h>

// ---------------------------------------------------------------------------
// 2-layer GCN on MI355X.
// R1: 3-phase scan. R2: h fp16 + lane-group agg. R3: two-level LDS counting
//     sort for CSR build (no global float atomics, coalesced slab writes).
// R5: (a) agg: 4 edges in flight for C=128 (16 lanes x float4/edge), 8 for
//     C=64 — halves VALU ops/byte, doubles memory-level parallelism.
//     (b) GEMMs moved to fp16 MFMA (mfma_f32_16x16x32_f16), W pre-transposed
//     fp16 once; X staged fp16 in LDS with +8-half pad (2-way-free banks).
// ---------------------------------------------------------------------------

typedef _Float16 half8 __attribute__((ext_vector_type(8)));
typedef float f32x4 __attribute__((ext_vector_type(4)));

constexpr int BK_SHIFT = 7;               // 128 nodes per bucket
constexpr int BK_NODES = 1 << BK_SHIFT;
constexpr int NB_MAX   = 1024;
constexpr int SLAB     = 2560;            // mean 2046 + 11 sigma
constexpr int P1_EPT   = 32;
constexpr int P1_EDGES = 256 * P1_EPT;    // 8192

// ---- pass 1: LDS counting sort of 8192 edges into coarse buckets ----
__global__ __launch_bounds__(256) void k_p1(const int* __restrict__ src,
                                            const int* __restrict__ dst, int E,
                                            int NB, int* __restrict__ bfill,
                                            unsigned* __restrict__ slab) {
  __shared__ unsigned stage[P1_EDGES];
  __shared__ unsigned short bidp[P1_EDGES];
  __shared__ int hist[NB_MAX];
  __shared__ int lbase[NB_MAX];
  __shared__ int goff[NB_MAX];
  __shared__ int part[256];

  const int t = threadIdx.x;
  const long base = (long)blockIdx.x * P1_EDGES;
  const int nval = (int)(((long)E - base < (long)P1_EDGES) ? (E - base) : P1_EDGES);

  for (int i = t; i < NB; i += 256) hist[i] = 0;
  __syncthreads();

  int eb[P1_EPT];
  unsigned ev[P1_EPT];
#pragma unroll
  for (int i = 0; i < P1_EPT; ++i) {
    long e = base + t + i * 256;
    int b = -1;
    unsigned v = 0;
    if (e < E) {
      int d = dst[e];
      int s = src[e];
      b = d >> BK_SHIFT;
      v = ((unsigned)(d & (BK_NODES - 1)) << 17) | (unsigned)s;
      atomicAdd(&hist[b], 1);
    }
    eb[i] = b;
    ev[i] = v;
  }
  __syncthreads();

  int lc[4];
  int lsum = 0;
#pragma unroll
  for (int j = 0; j < 4; ++j) {
    int b = t * 4 + j;
    lc[j] = (b < NB) ? hist[b] : 0;
    lsum += lc[j];
  }
  part[t] = lsum;
  __syncthreads();
  for (int o = 1; o < 256; o <<= 1) {
    int a = (t >= o) ? part[t - o] : 0;
    __syncthreads();
    part[t] += a;
    __syncthreads();
  }
  int run = part[t] - lsum;
#pragma unroll
  for (int j = 0; j < 4; ++j) {
    int b = t * 4 + j;
    if (b < NB) lbase[b] = run;
    run += lc[j];
  }
  __syncthreads();

  for (int b = t; b < NB; b += 256) {
    int len = hist[b];
    int g = len ? atomicAdd(&bfill[b], len) : 0;
    goff[b] = b * SLAB + g - lbase[b];
  }
  __syncthreads();

#pragma unroll
  for (int i = 0; i < P1_EPT; ++i) {
    if (eb[i] >= 0) {
      int p = atomicAdd(&lbase[eb[i]], 1);
      stage[p] = ev[i];
      bidp[p] = (unsigned short)eb[i];
    }
  }
  __syncthreads();

  for (int p = t; p < nval; p += 256) {
    int b = bidp[p];
    slab[goff[b] + p] = stage[p];
  }
}

__global__ __launch_bounds__(1024) void k_bscan(const int* __restrict__ bfill, int NB,
                                                int* __restrict__ bbase) {
  __shared__ int sm[1024];
  const int t = threadIdx.x;
  int v = (t < NB) ? bfill[t] : 0;
  sm[t] = v;
  __syncthreads();
  for (int o = 1; o < 1024; o <<= 1) {
    int a = (t >= o) ? sm[t - o] : 0;
    __syncthreads();
    sm[t] += a;
    __syncthreads();
  }
  if (t < NB) bbase[t] = sm[t] - v;
}

__global__ __launch_bounds__(256) void k_p2(const unsigned* __restrict__ slab,
                                            const int* __restrict__ bfill,
                                            const int* __restrict__ bbase, int N,
                                            int* __restrict__ deg,
                                            int* __restrict__ row_ptr,
                                            float* __restrict__ dinv,
                                            int* __restrict__ ssrc) {
  __shared__ int hist[BK_NODES];
  __shared__ int lb[BK_NODES];
  const int b = blockIdx.x;
  const int t = threadIdx.x;
  const int len = bfill[b];
  const int gbase = bbase[b];
  const unsigned* seg = slab + (size_t)b * SLAB;

  if (t < BK_NODES) hist[t] = 0;
  __syncthreads();
  for (int i = t; i < len; i += 256) atomicAdd(&hist[seg[i] >> 17], 1);
  __syncthreads();

  if (t < BK_NODES) lb[t] = hist[t];
  __syncthreads();
  for (int o = 1; o < BK_NODES; o <<= 1) {
    int a = 0;
    if (t < BK_NODES && t >= o) a = lb[t - o];
    __syncthreads();
    if (t < BK_NODES) lb[t] += a;
    __syncthreads();
  }

  int n = b * BK_NODES + t;
  if (t < BK_NODES && n < N) {
    int d = hist[t];
    deg[n] = d;
    row_ptr[n] = gbase + lb[t] - d;
    dinv[n] = rsqrtf((float)(d + 1));
  }
  __syncthreads();
  if (t < BK_NODES) lb[t] -= hist[t];
  __syncthreads();

  for (int i = t; i < len; i += 256) {
    unsigned v = seg[i];
    int l = v >> 17;
    int p = atomicAdd(&lb[l], 1);
    ssrc[gbase + p] = (int)(v & 0x1FFFF);
  }
}

// ---- prep: W (fp32, [K][NC]) -> Wt (fp16, [NC][K]) ----
__global__ __launch_bounds__(256) void k_prep(const float* __restrict__ W1,
                                              const float* __restrict__ W2,
                                              __half* __restrict__ Wt1,
                                              __half* __restrict__ Wt2) {
  int i = blockIdx.x * blockDim.x + threadIdx.x;
  if (i < 16384) {            // W1: 128x128
    int k = i >> 7, n = i & 127;
    Wt1[n * 128 + k] = __float2half(W1[i]);
  } else if (i < 24576) {     // W2: 128x64
    int j = i - 16384;
    int k = j >> 6, n = j & 63;
    Wt2[n * 128 + k] = __float2half(W2[j]);
  }
}

// ---- MFMA GEMM: H[row][c] = (sum_k X[row][k]*W[k][c]) * dinv[row], fp16 out.
// A-frag: m = lane&15, k-chunk = (lane>>4)*8 (order cancels between A and B).
// D: col = lane&15, row = (lane>>4)*4 + reg   [verified mapping].
template <int NC>
__global__ __launch_bounds__(256) void k_gemm(const float* __restrict__ X,
                                              const __half* __restrict__ Wt,
                                              const float* __restrict__ dinv,
                                              __half* __restrict__ H, int N) {
  constexpr int K = 128;
  constexpr int BM = 64;
  constexpr int LDK = K + 8;   // half units; 272B row pitch (16B-aligned, 2-way banks)
  constexpr int NT = NC / 16;
  __shared__ _Float16 xs[BM * LDK];
  __shared__ _Float16 wl[NC * LDK];

  const int t = threadIdx.x;
  const int r0 = blockIdx.x * BM;

  // stage X fp32 -> fp16 LDS (ds_write_b64 per float4)
  for (int i = t; i < BM * (K / 4); i += 256) {
    int row = i >> 5, kg = i & 31;
    float4 v = make_float4(0.f, 0.f, 0.f, 0.f);
    if (r0 + row < N)
      v = *reinterpret_cast<const float4*>(X + (size_t)(r0 + row) * K + 4 * kg);
    union { _Float16 h[4]; unsigned long long u; } pk;
    pk.h[0] = (_Float16)v.x; pk.h[1] = (_Float16)v.y;
    pk.h[2] = (_Float16)v.z; pk.h[3] = (_Float16)v.w;
    *reinterpret_cast<unsigned long long*>(&xs[row * LDK + 4 * kg]) = pk.u;
  }
  // stage Wt fp16 -> LDS (16B chunks)
  for (int i = t; i < NC * (K / 8); i += 256) {
    int n = i >> 4, kc = i & 15;
    float4 raw = *reinterpret_cast<const float4*>(Wt + (size_t)n * K + 8 * kc);
    *reinterpret_cast<float4*>(&wl[n * LDK + 8 * kc]) = raw;
  }
  __syncthreads();

  const int w = t >> 6;
  const int lane = t & 63;
  const int lm = lane & 15;
  const int lg = lane >> 4;

  half8 a[4];
#pragma unroll
  for (int kt = 0; kt < 4; ++kt)
    a[kt] = *reinterpret_cast<const half8*>(&xs[(w * 16 + lm) * LDK + kt * 32 + lg * 8]);

  f32x4 acc[NT];
#pragma unroll
  for (int nt = 0; nt < NT; ++nt) acc[nt] = (f32x4){0.f, 0.f, 0.f, 0.f};

#pragma unroll
  for (int nt = 0; nt < NT; ++nt) {
#pragma unroll
    for (int kt = 0; kt < 4; ++kt) {
      half8 b = *reinterpret_cast<const half8*>(
          &wl[(nt * 16 + lm) * LDK + kt * 32 + lg * 8]);
      acc[nt] = __builtin_amdgcn_mfma_f32_16x16x32_f16(a[kt], b, acc[nt], 0, 0, 0);
    }
  }

  float dv[4];
#pragma unroll
  for (int r = 0; r < 4; ++r) {
    int row = r0 + w * 16 + lg * 4 + r;
    dv[r] = (row < N) ? dinv[row] : 0.f;
  }
#pragma unroll
  for (int nt = 0; nt < NT; ++nt) {
#pragma unroll
    for (int r = 0; r < 4; ++r) {
      int row = r0 + w * 16 + lg * 4 + r;
      if (row < N)
        H[(size_t)row * NC + nt * 16 + lm] = __float2half(acc[nt][r] * dv[r]);
    }
  }
}

// ---- aggregation C=128: 16 lanes/edge (float4 of __half2), 4 edges in flight ----
template <bool RELU>
__global__ __launch_bounds__(256) void k_agg128(const __half* __restrict__ H,
                                                const int* __restrict__ row_ptr,
                                                const int* __restrict__ deg,
                                                const int* __restrict__ ssrc,
                                                const float* __restrict__ dinv,
                                                const float* __restrict__ bias,
                                                float* __restrict__ out, int N) {
  const int wave = threadIdx.x >> 6;
  const int lane = threadIdx.x & 63;
  const int n = blockIdx.x * 4 + wave;
  if (n >= N) return;

  const int eh = lane >> 4;   // 0..3: edge slot
  const int cl = lane & 15;   // 8-col chunk
  const int e0 = row_ptr[n];
  const int e1 = e0 + deg[n];
  const float dv = dinv[n];

  float acc[8] = {0.f, 0.f, 0.f, 0.f, 0.f, 0.f, 0.f, 0.f};
  auto gat = [&](int s) {
    float4 raw = *reinterpret_cast<const float4*>(H + (size_t)s * 128 + 8 * cl);
    const __half2* hp = reinterpret_cast<const __half2*>(&raw);
#pragma unroll
    for (int j = 0; j < 4; ++j) {
      float2 f = __half22float2(hp[j]);
      acc[2 * j] += f.x;
      acc[2 * j + 1] += f.y;
    }
  };
  if (eh == 0) gat(n);  // self loop
  int e = e0;
  for (; e + 8 <= e1; e += 8) {
    int sA = ssrc[e + eh];
    int sB = ssrc[e + 4 + eh];
    gat(sA);
    gat(sB);
  }
  if (e + 4 <= e1) { gat(ssrc[e + eh]); e += 4; }
  if (e + eh < e1) gat(ssrc[e + eh]);

#pragma unroll
  for (int j = 0; j < 8; ++j) {
    acc[j] += __shfl_xor(acc[j], 16);
    acc[j] += __shfl_xor(acc[j], 32);
  }
  if (eh == 0) {
    float4 b0 = *reinterpret_cast<const float4*>(bias + 8 * cl);
    float4 b1 = *reinterpret_cast<const float4*>(bias + 8 * cl + 4);
    float4 o0 = make_float4(acc[0] * dv + b0.x, acc[1] * dv + b0.y,
                            acc[2] * dv + b0.z, acc[3] * dv + b0.w);
    float4 o1 = make_float4(acc[4] * dv + b1.x, acc[5] * dv + b1.y,
                            acc[6] * dv + b1.z, acc[7] * dv + b1.w);
    if (RELU) {
      o0.x = fmaxf(o0.x, 0.f); o0.y = fmaxf(o0.y, 0.f);
      o0.z = fmaxf(o0.z, 0.f); o0.w = fmaxf(o0.w, 0.f);
      o1.x = fmaxf(o1.x, 0.f); o1.y = fmaxf(o1.y, 0.f);
      o1.z = fmaxf(o1.z, 0.f); o1.w = fmaxf(o1.w, 0.f);
    }
    *reinterpret_cast<float4*>(out + (size_t)n * 128 + 8 * cl) = o0;
    *reinterpret_cast<float4*>(out + (size_t)n * 128 + 8 * cl + 4) = o1;
  }
}

// ---- aggregation C=64: 8 lanes/edge, 8 edges in flight ----
__global__ __launch_bounds__(256) void k_agg64(const __half* __restrict__ H,
                                               const int* __restrict__ row_ptr,
                                               const int* __restrict__ deg,
                                               const int* __restrict__ ssrc,
                                               const float* __restrict__ dinv,
                                               const float* __restrict__ bias,
                                               float* __restrict__ out, int N) {
  const int wave = threadIdx.x >> 6;
  const int lane = threadIdx.x & 63;
  const int n = blockIdx.x * 4 + wave;
  if (n >= N) return;

  const int eh = lane >> 3;   // 0..7
  const int cl = lane & 7;    // 8-col chunk
  const int e0 = row_ptr[n];
  const int e1 = e0 + deg[n];
  const float dv = dinv[n];

  float acc[8] = {0.f, 0.f, 0.f, 0.f, 0.f, 0.f, 0.f, 0.f};
  auto gat = [&](int s) {
    float4 raw = *reinterpret_cast<const float4*>(H + (size_t)s * 64 + 8 * cl);
    const __half2* hp = reinterpret_cast<const __half2*>(&raw);
#pragma unroll
    for (int j = 0; j < 4; ++j) {
      float2 f = __half22float2(hp[j]);
      acc[2 * j] += f.x;
      acc[2 * j + 1] += f.y;
    }
  };
  if (eh == 0) gat(n);
  int e = e0;
  for (; e + 16 <= e1; e += 16) {
    int sA = ssrc[e + eh];
    int sB = ssrc[e + 8 + eh];
    gat(sA);
    gat(sB);
  }
  if (e + 8 <= e1) { gat(ssrc[e + eh]); e += 8; }
  if (e + eh < e1) gat(ssrc[e + eh]);

#pragma unroll
  for (int j = 0; j < 8; ++j) {
    acc[j] += __shfl_xor(acc[j], 8);
    acc[j] += __shfl_xor(acc[j], 16);
    acc[j] += __shfl_xor(acc[j], 32);
  }
  if (eh == 0) {
    float4 b0 = *reinterpret_cast<const float4*>(bias + 8 * cl);
    float4 b1 = *reinterpret_cast<const float4*>(bias + 8 * cl + 4);
    float4 o0 = make_float4(acc[0] * dv + b0.x, acc[1] * dv + b0.y,
                            acc[2] * dv + b0.z, acc[3] * dv + b0.w);
    float4 o1 = make_float4(acc[4] * dv + b1.x, acc[5] * dv + b1.y,
                            acc[6] * dv + b1.z, acc[7] * dv + b1.w);
    *reinterpret_cast<float4*>(out + (size_t)n * 64 + 8 * cl) = o0;
    *reinterpret_cast<float4*>(out + (size_t)n * 64 + 8 * cl + 4) = o1;
  }
}

extern "C" void kernel_launch(void* const* d_in, const int* in_sizes, int n_in,
                              void* d_out, int out_size, void* d_ws, size_t ws_size,
                              hipStream_t stream) {
  const float* x = (const float*)d_in[0];
  const int* ei = (const int*)d_in[1];
  const float* W1 = (const float*)d_in[2];
  const float* b1 = (const float*)d_in[3];
  const float* W2 = (const float*)d_in[4];
  const float* b2 = (const float*)d_in[5];

  const int K = 128;
  const int N = in_sizes[0] / K;     // 100000
  const int E = in_sizes[1] / 2;     // 1600000
  const int NB = (N + BK_NODES - 1) >> BK_SHIFT;  // 782
  if (NB > NB_MAX) return;

  const int* src = ei;
  const int* dst = ei + E;

  size_t off = 0;
  auto carve = [&](size_t bytes) {
    size_t o = off;
    off += (bytes + 255) & ~(size_t)255;
    return o;
  };
  char* ws = (char*)d_ws;
  int*      deg     = (int*)(ws + carve((size_t)N * 4));
  int*      row_ptr = (int*)(ws + carve((size_t)N * 4));
  float*    dinv    = (float*)(ws + carve((size_t)N * 4));
  int*      bfill   = (int*)(ws + carve((size_t)NB * 4));
  int*      bbase   = (int*)(ws + carve((size_t)NB * 4));
  __half*   wt1     = (__half*)(ws + carve(16384 * 2));
  __half*   wt2     = (__half*)(ws + carve(8192 * 2));
  unsigned* slab    = (unsigned*)(ws + carve((size_t)NB * SLAB * 4));
  int*      ssrc    = (int*)(ws + carve((size_t)E * 4));
  __half*   h1      = (__half*)(ws + carve((size_t)N * K * 2));  // reused as h2
  float*    out1    = (float*)(ws + carve((size_t)N * K * 4));
  if (off > ws_size) return;

  __half* h2 = h1;
  float* out2 = (float*)d_out;

  hipMemsetAsync(bfill, 0, (size_t)NB * 4, stream);
  k_prep<<<96, 256, 0, stream>>>(W1, W2, wt1, wt2);
  const int nwg1 = (E + P1_EDGES - 1) / P1_EDGES;
  k_p1<<<nwg1, 256, 0, stream>>>(src, dst, E, NB, bfill, slab);
  k_bscan<<<1, 1024, 0, stream>>>(bfill, NB, bbase);
  k_p2<<<NB, 256, 0, stream>>>(slab, bfill, bbase, N, deg, row_ptr, dinv, ssrc);

  k_gemm<128><<<(N + 63) / 64, 256, 0, stream>>>(x, wt1, dinv, h1, N);
  k_agg128<true><<<(N + 3) / 4, 256, 0, stream>>>(h1, row_ptr, deg, ssrc, dinv,
                                                  b1, out1, N);
  k_gemm<64><<<(N + 63) / 64, 256, 0, stream>>>(out1, wt2, dinv, h2, N);
  k_agg64<<<(N + 3) / 4, 256, 0, stream>>>(h2, row_ptr, deg, ssrc, dinv,
                                           b2, out2, N);
  (void)n_in; (void)out_size;
}